// Round 10
// baseline (229.280 us; speedup 1.0000x reference)
//
#include <hip/hip_runtime.h>
#include <cstdint>
#include <cstddef>

#define BB   32
#define NN   1024
#define FIN  128
#define FOUT 128

typedef __attribute__((ext_vector_type(8))) short bf16x8;
typedef __attribute__((ext_vector_type(4))) float f32x4;

__device__ __forceinline__ unsigned int f2bf(float f) {
    union { float f; unsigned int u; } v; v.f = f;
    unsigned int u = v.u;
    return (u + 0x7FFFu + ((u >> 16) & 1u)) >> 16;   // RNE fp32 -> bf16
}
__device__ __forceinline__ unsigned int pack2(float a, float b) {
    return f2bf(a) | (f2bf(b) << 16);
}

// async global -> LDS DMA, 16 B per lane; LDS dst is wave-uniform base,
// HW scatters lane i to base + i*16 (m97/m104 semantics)
__device__ __forceinline__ void load_lds16(const void* g, void* l) {
    __builtin_amdgcn_global_load_lds(
        (const __attribute__((address_space(1))) unsigned int*)g,
        (__attribute__((address_space(3))) unsigned int*)l, 16, 0, 0);
}

// ---------------------------------------------------------------------------
// Kernel 1: Yt[b][o][m] = sum_f node[b][m][f] * W[o][f]  (bf16, [B][FOUT][NN])
// (multiply-verified; ~3 us)
// ---------------------------------------------------------------------------
__global__ __launch_bounds__(256) void y_kernel(const float* __restrict__ node,
                                                const float* __restrict__ W,
                                                unsigned short* __restrict__ Yt) {
    __shared__ unsigned short Wlds[128 * 136];
    __shared__ unsigned short Nlds[64 * 136];

    const int tid = threadIdx.x;
    const int bid = blockIdx.x;
    const int b   = bid >> 4;
    const int m0  = (bid & 15) * 64;

    #pragma unroll
    for (int i = 0; i < 16; ++i) {
        const int idx = i * 256 + tid;
        const int row = idx >> 5;
        const int c   = (idx & 31) * 4;
        float4 v = ((const float4*)W)[idx];
        uint2 p; p.x = pack2(v.x, v.y); p.y = pack2(v.z, v.w);
        *(uint2*)&Wlds[row * 136 + c] = p;
    }
    {
        const float* base = node + ((size_t)b * NN + m0) * FIN;
        #pragma unroll
        for (int i = 0; i < 8; ++i) {
            const int idx = i * 256 + tid;
            const int row = idx >> 5;
            const int c   = (idx & 31) * 4;
            float4 v = *(const float4*)(base + row * FIN + c);
            uint2 p; p.x = pack2(v.x, v.y); p.y = pack2(v.z, v.w);
            *(uint2*)&Nlds[row * 136 + c] = p;
        }
    }
    __syncthreads();

    const int w = tid >> 6, lane = tid & 63;
    const int wo = w * 32;
    const int lcol = lane & 15, lk = (lane >> 4) * 8;

    f32x4 acc[2][4] = {};
    #pragma unroll
    for (int kc = 0; kc < 4; ++kc) {
        const int kof = kc * 32 + lk;
        bf16x8 a[2], bb[4];
        #pragma unroll
        for (int mi = 0; mi < 2; ++mi)
            a[mi] = *(const bf16x8*)&Wlds[(wo + mi*16 + lcol) * 136 + kof];
        #pragma unroll
        for (int ni = 0; ni < 4; ++ni)
            bb[ni] = *(const bf16x8*)&Nlds[(ni*16 + lcol) * 136 + kof];
        #pragma unroll
        for (int mi = 0; mi < 2; ++mi)
            #pragma unroll
            for (int ni = 0; ni < 4; ++ni)
                acc[mi][ni] = __builtin_amdgcn_mfma_f32_16x16x32_bf16(
                    a[mi], bb[ni], acc[mi][ni], 0, 0, 0);
    }
    __syncthreads();

    unsigned short* Ylds = Wlds;
    const int rq = (lane >> 4) * 4;
    #pragma unroll
    for (int mi = 0; mi < 2; ++mi)
        #pragma unroll
        for (int ni = 0; ni < 4; ++ni)
            #pragma unroll
            for (int r = 0; r < 4; ++r) {
                const int o = wo + mi * 16 + rq + r;
                const int m = ni * 16 + lcol;
                Ylds[o * 72 + m] = (unsigned short)f2bf(acc[mi][ni][r]);
            }
    __syncthreads();

    {
        const int oq = tid >> 3, c = (tid & 7) * 8;
        #pragma unroll
        for (int j = 0; j < 4; ++j) {
            const int o = oq + 32 * j;
            uint4 v = *(const uint4*)&Ylds[o * 72 + c];
            *(uint4*)(Yt + ((size_t)b * FOUT + o) * NN + m0 + c) = v;
        }
    }
}

// ---------------------------------------------------------------------------
// Kernel 2 v13: r8's single-barrier ring-4 depth-2 skeleton x r9's BM=64 /
// 2-blocks-per-CU geometry — the untested quadrant.
// Cross-round law: staged delivery rate tracks blocks/CU (1 -> ~4.8 B/cy/CU,
// 2 -> 6.6, 4+ -> 8-9) while direct loads sustain 6.5 TB/s; the degradation
// is the per-step burst/convoy of the barrier skeleton. r8 removed the 2nd
// barrier + widened wait slack to 2 steps but only at 1 block/CU; here the
// same skeleton runs at 2 blocks/CU:
//   K_STEP=32; buffer = A[64][32]f32 (8KB) + B[128][32]bf16 (8KB) = 16 KB;
//   ring of 4 = 64 KB LDS -> 2 blocks/CU, 16 waves/CU (4/SIMD).
//   All 8 waves stage exactly 2 DMA/step (waves 0-3: A, 4-7: B) -> uniform
//   vmcnt(4); awaited loads were issued TWO steps (~2600 cy) earlier.
//   ONE barrier/step: buf (t+2)&3 was last read at t-2, and iter t-1's
//   barrier (after every wave's COMPUTE(t-2)) protects it (r8 argument).
// Fragment offsets = r8's K_STEP=32 formulas; COMPUTE / pack / rowsum /
// epilogue byte-identical to the passing r8/r9 kernels.
// ---------------------------------------------------------------------------
#define ABYTES 8192                  // A: [64][32] fp32
#define BBYTES 8192                  // B: [128][32] bf16
#define BUFB   (ABYTES + BBYTES)     // 16 KB per buffer

__global__ __launch_bounds__(512, 4) void gcn_kernel(const float* __restrict__ adj,
                                                     const unsigned short* __restrict__ Yt,
                                                     const float* __restrict__ bias,
                                                     float* __restrict__ out) {
    __shared__ __align__(16) char smem[4 * BUFB];    // 64 KB

    const int tid  = threadIdx.x;
    const int lane = tid & 63;
    const int w    = tid >> 6;                        // 0..7

    const int raw = blockIdx.x;                       // grid 512
    const int bid = (raw & 7) * 64 + (raw >> 3);      // XCD-contiguous, bijective
    const int b   = bid >> 4;
    const int n0  = (bid & 15) * 64;

    const int lcol = lane & 15, q = lane >> 4;
    const int wm = (w & 3) * 16;                      // row group (0..48)
    const int wn = (w >> 2) * 64;                     // col half  (0 / 64)

    // ---- staging role (wave-uniform); src carries within-row XOR swizzle,
    //      LDS linear; reader folds the same XOR (both-sides rule) ----
    const char* src0; const char* src1;
    char* dst0; char* dst1;
    int sstride;
    if (w < 4) {
        // A: 8 instrs/step; instr i covers rows i*8..i*8+7 (8 lanes/row,
        // 16B chunk c = lane&7, fetched chunk g = c ^ (row&7))
        const int i0 = 2 * w, i1 = 2 * w + 1;
        const int r0 = i0 * 8 + (lane >> 3), r1 = i1 * 8 + (lane >> 3);
        const int g0 = (lane & 7) ^ (r0 & 7), g1 = (lane & 7) ^ (r1 & 7);
        src0 = (const char*)(adj + ((size_t)(b * NN + n0 + r0)) * NN + g0 * 4);
        src1 = (const char*)(adj + ((size_t)(b * NN + n0 + r1)) * NN + g1 * 4);
        dst0 = smem + i0 * 1024;
        dst1 = smem + i1 * 1024;
        sstride = 128;                               // 32 fp32 per step
    } else {
        // B: 8 instrs/step; instr j covers rows o = j*16..j*16+15 (4 lanes/
        // row, 16B chunk c = lane&3, fetched g = c ^ (o&3))
        const int j0 = 2 * (w - 4), j1 = j0 + 1;
        const int o0 = j0 * 16 + (lane >> 2), o1 = j1 * 16 + (lane >> 2);
        const int g0 = (lane & 3) ^ (o0 & 3), g1 = (lane & 3) ^ (o1 & 3);
        src0 = (const char*)(Yt + ((size_t)(b * FOUT + o0)) * NN + g0 * 8);
        src1 = (const char*)(Yt + ((size_t)(b * FOUT + o1)) * NN + g1 * 8);
        dst0 = smem + ABYTES + j0 * 1024;
        dst1 = smem + ABYTES + j1 * 1024;
        sstride = 64;                                // 32 bf16 per step
    }

    // ---- fragment read byte-offsets within a buffer (swizzle folded in) ----
    // A row R: linear R*128B; reader wants global chunks 2q, 2q+1.
    const int R = wm + lcol, keyR = R & 7;
    const int offA0 = R * 128 + ((2 * q)     ^ keyR) * 16;
    const int offA1 = R * 128 + ((2 * q + 1) ^ keyR) * 16;
    // B row o: linear ABYTES + o*64B; reader wants global chunk q.
    int offB[4];
    #pragma unroll
    for (int ni = 0; ni < 4; ++ni) {
        const int o = wn + ni * 16 + lcol;
        offB[ni] = ABYTES + o * 64 + (q ^ (o & 3)) * 16;
    }

    f32x4 acc[4] = {};
    float rsum = 0.f;

    #define STAGE(buf, s)                                                   \
        do {                                                                \
            load_lds16(src0 + (s) * sstride, dst0 + (buf) * BUFB);          \
            load_lds16(src1 + (s) * sstride, dst1 + (buf) * BUFB);          \
        } while (0)

    #define COMPUTE(buf)                                                    \
        do {                                                                \
            const char* base = smem + (buf) * BUFB;                         \
            const float4 f0 = *(const float4*)(base + offA0);               \
            const float4 f1 = *(const float4*)(base + offA1);               \
            rsum += ((f0.x + f0.y) + (f0.z + f0.w))                         \
                  + ((f1.x + f1.y) + (f1.z + f1.w));                        \
            uint4 pk;                                                       \
            pk.x = pack2(f0.x, f0.y); pk.y = pack2(f0.z, f0.w);             \
            pk.z = pack2(f1.x, f1.y); pk.w = pack2(f1.z, f1.w);             \
            const bf16x8 a = *(const bf16x8*)&pk;                           \
            _Pragma("unroll")                                               \
            for (int ni = 0; ni < 4; ++ni) {                                \
                const bf16x8 bbf = *(const bf16x8*)(base + offB[ni]);       \
                acc[ni] = __builtin_amdgcn_mfma_f32_16x16x32_bf16(          \
                    a, bbf, acc[ni], 0, 0, 0);                              \
            }                                                               \
        } while (0)

    // prologue: steps 0,1 -> bufs 0,1 (4 loads/wave in flight)
    STAGE(0, 0);
    STAGE(1, 1);

    // steady state: stage t+2 into ring, wait step t (vmcnt(4): t+1,t+2
    // outstanding; per-wave vmem completion is in-order), ONE barrier,
    // compute. 28 iters; tail t=28..31.
    #pragma unroll 4
    for (int t = 0; t < 28; ++t) {
        STAGE((t + 2) & 3, t + 2);
        asm volatile("s_waitcnt vmcnt(4)" ::: "memory");
        __builtin_amdgcn_s_barrier();
        COMPUTE(t & 3);
    }
    // t=28
    STAGE(2, 30);
    asm volatile("s_waitcnt vmcnt(4)" ::: "memory");
    __builtin_amdgcn_s_barrier();
    COMPUTE(0);
    // t=29
    STAGE(3, 31);
    asm volatile("s_waitcnt vmcnt(4)" ::: "memory");
    __builtin_amdgcn_s_barrier();
    COMPUTE(1);
    // t=30
    asm volatile("s_waitcnt vmcnt(2)" ::: "memory");
    __builtin_amdgcn_s_barrier();
    COMPUTE(2);
    // t=31
    asm volatile("s_waitcnt vmcnt(0)" ::: "memory");
    __builtin_amdgcn_s_barrier();
    COMPUTE(3);
    #undef STAGE
    #undef COMPUTE

    // full row sums: lanes sharing lcol hold disjoint k-slices of row wm+lcol
    rsum += __shfl_xor(rsum, 16);
    rsum += __shfl_xor(rsum, 32);

    // D layout: col = lane&15 (o), row-in-tile = q*4 + r.
    // 1/rowsum for row wm+(rq+r): lane rq+r holds it (lcol = rq+r).
    const int rq = q * 4;
    float sc[4];
    #pragma unroll
    for (int r = 0; r < 4; ++r) sc[r] = 1.0f / __shfl(rsum, rq + r);

    float* outB = out + ((size_t)(b * NN + n0 + wm)) * FOUT;
    #pragma unroll
    for (int ni = 0; ni < 4; ++ni) {
        const float bc = bias[wn + ni * 16 + lcol];
        #pragma unroll
        for (int r = 0; r < 4; ++r) {
            float v = acc[ni][r] * sc[r] + bc;
            v = (v >= 0.f) ? v : 0.01f * v;
            outB[(size_t)(rq + r) * FOUT + wn + ni * 16 + lcol] = v;
        }
    }
}

extern "C" void kernel_launch(void* const* d_in, const int* in_sizes, int n_in,
                              void* d_out, int out_size, void* d_ws, size_t ws_size,
                              hipStream_t stream) {
    const float* node = (const float*)d_in[0];   // [32,1024,128]
    const float* adj  = (const float*)d_in[1];   // [32,1024,1024]
    const float* W    = (const float*)d_in[2];   // [128,128]
    const float* bias = (const float*)d_in[3];   // [128]
    float* out = (float*)d_out;                  // [32,1024,128] fp32
    unsigned short* Yt = (unsigned short*)d_ws;  // [32,128,1024] bf16 = 8 MiB

    hipLaunchKernelGGL(y_kernel,   dim3(512), dim3(256), 0, stream, node, W, Yt);
    hipLaunchKernelGGL(gcn_kernel, dim3(512), dim3(512), 0, stream, adj, Yt, bias, out);
}